// Round 1
// baseline (374.071 us; speedup 1.0000x reference)
//
#include <hip/hip_runtime.h>
#include <hip/hip_bf16.h>
#include <math.h>

typedef short bf16x8 __attribute__((ext_vector_type(8)));
typedef float f32x4 __attribute__((ext_vector_type(4)));
typedef short short4v __attribute__((ext_vector_type(4)));
typedef short short8v __attribute__((ext_vector_type(8)));

__device__ __forceinline__ short f2bf(float f) {
  unsigned u = __builtin_bit_cast(unsigned, f);
  unsigned r = (u + 0x7FFFu + ((u >> 16) & 1u)) >> 16;
  return (short)r;
}
__device__ __forceinline__ float bf2f(short s) {
  unsigned u = ((unsigned)(unsigned short)s) << 16;
  return __builtin_bit_cast(float, u);
}

typedef __attribute__((address_space(1))) const unsigned g_u32;
typedef __attribute__((address_space(3))) unsigned l_u32;
__device__ __forceinline__ void gload_lds16(const short* g, short* l) {
  __builtin_amdgcn_global_load_lds((g_u32*)g, (l_u32*)l, 16, 0, 0);
}

// ---------------- casts ----------------

// x (S=2048, B=8, D=1024) f32  ->  xb (B, S, D) bf16
__global__ __launch_bounds__(256) void k_cast_x(const float* __restrict__ x, short* __restrict__ xb) {
  int tid = blockIdx.x * 256 + threadIdx.x;   // 4,194,304 total, 4 elems each
  int d4 = tid & 255;
  int sb = tid >> 8;
  int s = sb & 2047;
  int b = sb >> 11;
  float4 v = *((const float4*)(x + (((size_t)s * 8 + b) << 10)) + d4);
  short4v o;
  o.x = f2bf(v.x); o.y = f2bf(v.y); o.z = f2bf(v.z); o.w = f2bf(v.w);
  *((short4v*)(xb + (((size_t)b * 2048 + s) << 10)) + d4) = o;
}

// Wq,Wk,Wv (1024,1024) f32 -> Wcat (3072,1024) bf16
__global__ __launch_bounds__(256) void k_cast_w(const float* __restrict__ Wq, const float* __restrict__ Wk,
                                                const float* __restrict__ Wv, short* __restrict__ Wcat) {
  int tid = blockIdx.x * 256 + threadIdx.x;   // 786,432
  int d4 = tid & 255;
  int n = tid >> 8;                            // 0..3071
  const float* src = (n < 1024) ? Wq : (n < 2048 ? Wk : Wv);
  int nl = n & 1023;
  float4 v = *((const float4*)(src + ((size_t)nl << 10)) + d4);
  short4v o;
  o.x = f2bf(v.x); o.y = f2bf(v.y); o.z = f2bf(v.z); o.w = f2bf(v.w);
  *((short4v*)(Wcat + ((size_t)n << 10)) + d4) = o;
}

__global__ __launch_bounds__(256) void k_cast_bias(const float* __restrict__ bq, const float* __restrict__ bk,
                                                   const float* __restrict__ bv, float* __restrict__ biascat) {
  int i = blockIdx.x * 256 + threadIdx.x;
  if (i < 3072) biascat[i] = (i < 1024) ? bq[i] : (i < 2048 ? bk[i & 1023] : bv[i & 1023]);
}

// ---------------- GEMM core (128x128 tile, BK=64, 4 waves in 2x2) ----------------
// C[128][128] += A[128 rows of LDA, K-contig] * B^T[128 rows of LDB, K-contig]
template <int LDA, int LDB>
__device__ __forceinline__ void gemm_core(const short* __restrict__ Ag, const short* __restrict__ Bg,
                                          int ksteps, short* As, short* Bs,
                                          f32x4 (&acc)[4][4], int tid) {
  const int lane = tid & 63;
  const int wid = tid >> 6;
  const int wr = wid >> 1, wc = wid & 1;
  for (int s = 0; s < ksteps; ++s) {
    const int k0 = s << 6;
#pragma unroll
    for (int i = 0; i < 4; ++i) {
      int ch = i * 256 + tid;          // 1024 16B-chunks: row=ch>>3, colchunk=ch&7
      int r = ch >> 3, cc = ch & 7;
      gload_lds16(Ag + (size_t)r * LDA + k0 + cc * 8, As + ch * 8);
    }
#pragma unroll
    for (int i = 0; i < 4; ++i) {
      int ch = i * 256 + tid;
      int r = ch >> 3, cc = ch & 7;
      gload_lds16(Bg + (size_t)r * LDB + k0 + cc * 8, Bs + ch * 8);
    }
    __syncthreads();
#pragma unroll
    for (int kk = 0; kk < 2; ++kk) {
      bf16x8 af[4], bfr[4];
#pragma unroll
      for (int mi = 0; mi < 4; ++mi)
        af[mi] = *(const bf16x8*)(As + (wr * 64 + mi * 16 + (lane & 15)) * 64 + kk * 32 + ((lane >> 4) << 3));
#pragma unroll
      for (int ni = 0; ni < 4; ++ni)
        bfr[ni] = *(const bf16x8*)(Bs + (wc * 64 + ni * 16 + (lane & 15)) * 64 + kk * 32 + ((lane >> 4) << 3));
#pragma unroll
      for (int mi = 0; mi < 4; ++mi)
#pragma unroll
        for (int ni = 0; ni < 4; ++ni)
          acc[mi][ni] = __builtin_amdgcn_mfma_f32_16x16x32_bf16(af[mi], bfr[ni], acc[mi][ni], 0, 0, 0);
    }
    __syncthreads();
  }
}

// ---------------- QKV projection ----------------
// C (16384, 3072) = Xb (16384,1024) * Wcat^T + bias; split-stored bf16 into Q,K,V (each (B,S,1024))
__global__ __launch_bounds__(256) void k_proj(const short* __restrict__ Xb, const short* __restrict__ Wc,
                                              const float* __restrict__ biascat,
                                              short* __restrict__ Q, short* __restrict__ K, short* __restrict__ V) {
  __shared__ __align__(16) short As[128 * 64];
  __shared__ __align__(16) short Bs[128 * 64];
  int tid = threadIdx.x;
  int m0 = blockIdx.y << 7;
  int n0 = blockIdx.x << 7;
  f32x4 acc[4][4] = {};
  gemm_core<1024, 1024>(Xb + (size_t)m0 * 1024, Wc + (size_t)n0 * 1024, 16, As, Bs, acc, tid);
  int lane = tid & 63, wid = tid >> 6;
  int wr = wid >> 1, wc = wid & 1;
  int which = n0 >> 10;
  short* outb = (which == 0) ? Q : (which == 1 ? K : V);
  int nbase = n0 & 1023;
#pragma unroll
  for (int mi = 0; mi < 4; ++mi)
#pragma unroll
    for (int ni = 0; ni < 4; ++ni)
#pragma unroll
      for (int j = 0; j < 4; ++j) {
        int r = m0 + wr * 64 + mi * 16 + ((lane >> 4) << 2) + j;
        int cl = wc * 64 + ni * 16 + (lane & 15);
        float val = acc[mi][ni][j] + biascat[n0 + cl];
        outb[((size_t)r << 10) + nbase + cl] = f2bf(val);
      }
}

// ---------------- V transpose: V (B,S,A) -> Vt (B,A,S) ----------------
__global__ __launch_bounds__(256) void k_transpose(const short* __restrict__ V, short* __restrict__ Vt) {
  int b = blockIdx.z;
  int a0 = blockIdx.x << 6, s0 = blockIdx.y << 6;
  const short* Vb = V + ((size_t)b << 21);
  short* Vtb = Vt + ((size_t)b << 21);
  __shared__ short t[64][65];
  int tx = threadIdx.x & 63, ty = threadIdx.x >> 6;
#pragma unroll
  for (int i = 0; i < 16; ++i)
    t[ty + i * 4][tx] = Vb[((size_t)(s0 + ty + i * 4) << 10) + a0 + tx];
  __syncthreads();
#pragma unroll
  for (int i = 0; i < 16; ++i)
    Vtb[((size_t)(a0 + ty + i * 4) << 11) + s0 + tx] = t[tx][ty + i * 4];
}

// ---------------- QK^T (causal lower-tri tiles), scaled, bf16 scores ----------------
__global__ __launch_bounds__(256) void k_qk(const short* __restrict__ Q, const short* __restrict__ K,
                                            short* __restrict__ Sc) {
  int nt = blockIdx.x, mt = blockIdx.y, b = blockIdx.z;
  if (nt > mt) return;
  __shared__ __align__(16) short As[128 * 64];
  __shared__ __align__(16) short Bs[128 * 64];
  int tid = threadIdx.x;
  int m0 = mt << 7, n0 = nt << 7;
  const short* Qb = Q + ((size_t)b << 21);
  const short* Kb = K + ((size_t)b << 21);
  f32x4 acc[4][4] = {};
  gemm_core<1024, 1024>(Qb + (size_t)m0 * 1024, Kb + (size_t)n0 * 1024, 16, As, Bs, acc, tid);
  short* Sb = Sc + ((size_t)b << 22);
  int lane = tid & 63, wid = tid >> 6;
  int wr = wid >> 1, wc = wid & 1;
#pragma unroll
  for (int mi = 0; mi < 4; ++mi)
#pragma unroll
    for (int ni = 0; ni < 4; ++ni)
#pragma unroll
      for (int j = 0; j < 4; ++j) {
        int r = m0 + wr * 64 + mi * 16 + ((lane >> 4) << 2) + j;
        int c = n0 + wc * 64 + ni * 16 + (lane & 15);
        Sb[((size_t)r << 11) + c] = f2bf(acc[mi][ni][j] * 0.03125f);
      }
}

// ---------------- row softmax in-place, causal; zero-fill to diag-tile edge ----------------
__global__ __launch_bounds__(256) void k_softmax(short* __restrict__ Sc) {
  int row = blockIdx.x;                 // 16384 rows
  int b = row >> 11, q = row & 2047;
  short* Pr = Sc + ((size_t)b << 22) + ((size_t)q << 11);
  int T = ((q >> 7) + 1) << 7;          // padded causal length (multiple of 128)
  int tid = threadIdx.x, lane = tid & 63, wid = tid >> 6;
  int k0 = tid << 3;
  float v[8];
  if (k0 < T) {
    short8v raw = *(const short8v*)(Pr + k0);
#pragma unroll
    for (int j = 0; j < 8; ++j) v[j] = (k0 + j <= q) ? bf2f(raw[j]) : -__builtin_inff();
  } else {
#pragma unroll
    for (int j = 0; j < 8; ++j) v[j] = -__builtin_inff();
  }
  float mx = v[0];
#pragma unroll
  for (int j = 1; j < 8; ++j) mx = fmaxf(mx, v[j]);
  for (int off = 1; off < 64; off <<= 1) mx = fmaxf(mx, __shfl_xor(mx, off, 64));
  __shared__ float red[2][4];
  if (lane == 0) red[0][wid] = mx;
  __syncthreads();
  mx = fmaxf(fmaxf(red[0][0], red[0][1]), fmaxf(red[0][2], red[0][3]));
  float e[8], sum = 0.f;
#pragma unroll
  for (int j = 0; j < 8; ++j) {
    e[j] = exp2f((v[j] - mx) * 1.4426950408889634f);
    sum += e[j];
  }
  for (int off = 1; off < 64; off <<= 1) sum += __shfl_xor(sum, off, 64);
  if (lane == 0) red[1][wid] = sum;
  __syncthreads();
  sum = red[1][0] + red[1][1] + red[1][2] + red[1][3];
  float inv = 1.f / sum;
  if (k0 < T) {
    short8v o;
#pragma unroll
    for (int j = 0; j < 8; ++j) o[j] = (k0 + j <= q) ? f2bf(e[j] * inv) : (short)0;
    *(short8v*)(Pr + k0) = o;
  }
}

// ---------------- PV: out (S,B,A) f32 = P (B,S,S) * Vt (B,A,S)^T ----------------
__global__ __launch_bounds__(256) void k_pv(const short* __restrict__ P, const short* __restrict__ Vt,
                                            float* __restrict__ out) {
  int nt = blockIdx.x, mt = blockIdx.y, b = blockIdx.z;
  __shared__ __align__(16) short As[128 * 64];
  __shared__ __align__(16) short Bs[128 * 64];
  int tid = threadIdx.x;
  int m0 = mt << 7, n0 = nt << 7;
  const short* Pb = P + ((size_t)b << 22);
  const short* Vtb = Vt + ((size_t)b << 21);
  f32x4 acc[4][4] = {};
  gemm_core<2048, 2048>(Pb + (size_t)m0 * 2048, Vtb + (size_t)n0 * 2048, 2 * (mt + 1), As, Bs, acc, tid);
  int lane = tid & 63, wid = tid >> 6;
  int wr = wid >> 1, wc = wid & 1;
#pragma unroll
  for (int mi = 0; mi < 4; ++mi)
#pragma unroll
    for (int ni = 0; ni < 4; ++ni)
#pragma unroll
      for (int j = 0; j < 4; ++j) {
        int r = m0 + wr * 64 + mi * 16 + ((lane >> 4) << 2) + j;  // q index
        int c = n0 + wc * 64 + ni * 16 + (lane & 15);             // a index
        out[((size_t)r << 13) + ((size_t)b << 10) + c] = acc[mi][ni][j];
      }
}

extern "C" void kernel_launch(void* const* d_in, const int* in_sizes, int n_in,
                              void* d_out, int out_size, void* d_ws, size_t ws_size,
                              hipStream_t stream) {
  const float* x  = (const float*)d_in[0];
  const float* Wq = (const float*)d_in[1];
  const float* bq = (const float*)d_in[2];
  const float* Wk = (const float*)d_in[3];
  const float* bk = (const float*)d_in[4];
  const float* Wv = (const float*)d_in[5];
  const float* bv = (const float*)d_in[6];
  float* out = (float*)d_out;
  char* ws = (char*)d_ws;

  short* xb   = (short*)(ws);                    // 33,554,432 B (reused as Vt later)
  short* Wcat = (short*)(ws + 33554432);         //  6,291,456 B
  float* bias = (float*)(ws + 39845888);         //     12,288 B
  short* Q    = (short*)(ws + 39858176);         // 33,554,432 B
  short* K    = (short*)(ws + 73412608);         // 33,554,432 B
  short* V    = (short*)(ws + 106967040);        // 33,554,432 B
  short* Sc   = (short*)(ws + 140521472);        // 67,108,864 B -> total 207,630,336 B
  short* Vt   = xb;                              // alias: xb dead after k_proj

  k_cast_x<<<16384, 256, 0, stream>>>(x, xb);
  k_cast_w<<<3072, 256, 0, stream>>>(Wq, Wk, Wv, Wcat);
  k_cast_bias<<<12, 256, 0, stream>>>(bq, bk, bv, bias);
  k_proj<<<dim3(24, 128), 256, 0, stream>>>(xb, Wcat, bias, Q, K, V);
  k_transpose<<<dim3(16, 32, 8), 256, 0, stream>>>(V, Vt);
  k_qk<<<dim3(16, 16, 8), 256, 0, stream>>>(Q, K, Sc);
  k_softmax<<<16384, 256, 0, stream>>>(Sc);
  k_pv<<<dim3(8, 16, 8), 256, 0, stream>>>(Sc, Vt, out);
}

// Round 2
// 330.821 us; speedup vs baseline: 1.1307x; 1.1307x over previous
//
#include <hip/hip_runtime.h>
#include <hip/hip_bf16.h>
#include <math.h>

typedef short bf16x8 __attribute__((ext_vector_type(8)));
typedef float f32x4 __attribute__((ext_vector_type(4)));
typedef short short4v __attribute__((ext_vector_type(4)));
typedef short short8v __attribute__((ext_vector_type(8)));

__device__ __forceinline__ short f2bf(float f) {
  unsigned u = __builtin_bit_cast(unsigned, f);
  unsigned r = (u + 0x7FFFu + ((u >> 16) & 1u)) >> 16;
  return (short)r;
}
__device__ __forceinline__ float bf2f(short s) {
  unsigned u = ((unsigned)(unsigned short)s) << 16;
  return __builtin_bit_cast(float, u);
}

typedef __attribute__((address_space(1))) const unsigned g_u32;
typedef __attribute__((address_space(3))) unsigned l_u32;
__device__ __forceinline__ void gload_lds16(const short* g, short* l) {
  __builtin_amdgcn_global_load_lds((g_u32*)g, (l_u32*)l, 16, 0, 0);
}

// ---------------- casts ----------------

__global__ __launch_bounds__(256) void k_cast_x(const float* __restrict__ x, short* __restrict__ xb) {
  int tid = blockIdx.x * 256 + threadIdx.x;
  int d4 = tid & 255;
  int sb = tid >> 8;
  int s = sb & 2047;
  int b = sb >> 11;
  float4 v = *((const float4*)(x + (((size_t)s * 8 + b) << 10)) + d4);
  short4v o;
  o.x = f2bf(v.x); o.y = f2bf(v.y); o.z = f2bf(v.z); o.w = f2bf(v.w);
  *((short4v*)(xb + (((size_t)b * 2048 + s) << 10)) + d4) = o;
}

__global__ __launch_bounds__(256) void k_cast_w(const float* __restrict__ Wq, const float* __restrict__ Wk,
                                                const float* __restrict__ Wv, short* __restrict__ Wcat) {
  int tid = blockIdx.x * 256 + threadIdx.x;
  int d4 = tid & 255;
  int n = tid >> 8;
  const float* src = (n < 1024) ? Wq : (n < 2048 ? Wk : Wv);
  int nl = n & 1023;
  float4 v = *((const float4*)(src + ((size_t)nl << 10)) + d4);
  short4v o;
  o.x = f2bf(v.x); o.y = f2bf(v.y); o.z = f2bf(v.z); o.w = f2bf(v.w);
  *((short4v*)(Wcat + ((size_t)n << 10)) + d4) = o;
}

__global__ __launch_bounds__(256) void k_cast_bias(const float* __restrict__ bq, const float* __restrict__ bk,
                                                   const float* __restrict__ bv, float* __restrict__ biascat) {
  int i = blockIdx.x * 256 + threadIdx.x;
  if (i < 3072) biascat[i] = (i < 1024) ? bq[i] : (i < 2048 ? bk[i & 1023] : bv[i & 1023]);
}

// ---------------- 256x256-tile 8-phase GEMM core ----------------
// C[256][256] = A[256 rows, LDA, K-contig] * B^T[256 rows, LDB, K-contig]
// 512 threads = 8 waves in 2(M) x 4(N); per-wave output 128x64 -> acc[8][4].
// LDS: A ring [2buf][2half][128][64], B same. Swizzle: col ^= (row&7)<<4 bytes;
// staged linearly with inverse-swizzled global source (involution).
template <int LDA, int LDB>
__device__ __forceinline__ void gemm256_core(const short* __restrict__ Ag, const short* __restrict__ Bg,
                                             int NT, short* __restrict__ lds, f32x4 (&acc)[8][4], int tid) {
  const int lane = tid & 63;
  const int wid = tid >> 6;
  const int wm = wid >> 2, wn = wid & 3;
  short* As = lds;            // 32768 shorts
  short* Bs = lds + 32768;
  const int r15 = lane & 15;
  const int sx = (lane & 7) << 3;                 // swizzle XOR, elements
  const int co0 = (((lane >> 4) << 3)) ^ sx;      // kk=0
  const int co1 = (32 + ((lane >> 4) << 3)) ^ sx; // kk=1
  const int sw = tid >> 6, sl = tid & 63;

  auto stage_half = [&](const short* Gp, int ld, short* Lp, int k0) {
#pragma unroll
    for (int i = 0; i < 2; ++i) {
      int c = sw * 128 + i * 64 + sl;       // 1024 16B chunks
      int r = c >> 3, cc = c & 7;
      gload_lds16(Gp + (size_t)r * ld + k0 + (size_t)((cc ^ (r & 7)) << 3), Lp + c * 8);
    }
  };

  // prologue: K-tile 0 -> buf 0
  stage_half(Ag, LDA, As, 0);
  stage_half(Ag + (size_t)128 * LDA, LDA, As + 8192, 0);
  stage_half(Bg, LDB, Bs, 0);
  stage_half(Bg + (size_t)128 * LDB, LDB, Bs + 8192, 0);
  asm volatile("s_waitcnt vmcnt(0)" ::: "memory");
  __builtin_amdgcn_s_barrier();

  for (int t = 0; t < NT; ++t) {
    const int buf = t & 1, nbuf = buf ^ 1;
    const short* Abase = As + (buf * 2 + wm) * 8192;
    const short* Bbase = Bs + (buf * 2 + (wn >> 1)) * 8192 + (wn & 1) * 64 * 64;
    const int k1 = (t + 1) << 6;
    const bool more = (t + 1 < NT);
#pragma unroll
    for (int p = 0; p < 4; ++p) {
      const int mq = p >> 1, nq = p & 1;
      bf16x8 af[4][2], bfr[2][2];
#pragma unroll
      for (int fi = 0; fi < 4; ++fi) {
        const short* rp = Abase + (mq * 64 + fi * 16 + r15) * 64;
        af[fi][0] = *(const bf16x8*)(rp + co0);
        af[fi][1] = *(const bf16x8*)(rp + co1);
      }
#pragma unroll
      for (int nj = 0; nj < 2; ++nj) {
        const short* rp = Bbase + (nq * 32 + nj * 16 + r15) * 64;
        bfr[nj][0] = *(const bf16x8*)(rp + co0);
        bfr[nj][1] = *(const bf16x8*)(rp + co1);
      }
      if (p == 0 && more) {   // stage next K-tile's A halves (slot died last group)
        stage_half(Ag, LDA, As + nbuf * 16384, k1);
        stage_half(Ag + (size_t)128 * LDA, LDA, As + nbuf * 16384 + 8192, k1);
      }
      if (p == 1 && more) {   // B halves
        stage_half(Bg, LDB, Bs + nbuf * 16384, k1);
        stage_half(Bg + (size_t)128 * LDB, LDB, Bs + nbuf * 16384 + 8192, k1);
      }
      __builtin_amdgcn_s_barrier();
      __builtin_amdgcn_s_setprio(1);
#pragma unroll
      for (int fi = 0; fi < 4; ++fi)
#pragma unroll
        for (int nj = 0; nj < 2; ++nj)
#pragma unroll
          for (int kk = 0; kk < 2; ++kk)
            acc[mq * 4 + fi][nq * 2 + nj] =
                __builtin_amdgcn_mfma_f32_16x16x32_bf16(af[fi][kk], bfr[nj][kk],
                                                        acc[mq * 4 + fi][nq * 2 + nj], 0, 0, 0);
      __builtin_amdgcn_s_setprio(0);
      if (p == 3 && more) {
        // loads for K-tile t+1 were issued 2-3 phases ago; this drain is ~free
        asm volatile("s_waitcnt vmcnt(0)" ::: "memory");
      }
      __builtin_amdgcn_s_barrier();
    }
  }
}

// ---------------- QKV projection: (16384,3072) = Xb (16384,1024) * Wcat^T + bias ----------------
__global__ __launch_bounds__(512, 2) void k_proj(const short* __restrict__ Xb, const short* __restrict__ Wc,
                                                 const float* __restrict__ biascat,
                                                 short* __restrict__ Q, short* __restrict__ K, short* __restrict__ V) {
  __shared__ __align__(16) short lds[65536];
  int tid = threadIdx.x;
  int wg = blockIdx.x;                       // 768 blocks
  int swz = (wg & 7) * 96 + (wg >> 3);       // XCD swizzle (768 % 8 == 0, bijective)
  int mt = swz / 12, nt = swz % 12;
  int m0 = mt << 8, n0 = nt << 8;
  f32x4 acc[8][4] = {};
  gemm256_core<1024, 1024>(Xb + (size_t)m0 * 1024, Wc + (size_t)n0 * 1024, 16, lds, acc, tid);
  int lane = tid & 63, wid = tid >> 6;
  int wm = wid >> 2, wn = wid & 3;
  int r15 = lane & 15;
  int which = n0 >> 10;
  short* outb = (which == 0) ? Q : (which == 1 ? K : V);
  int nbase = n0 & 1023;
#pragma unroll
  for (int ni = 0; ni < 4; ++ni) {
    int cth = wn * 64 + ni * 16 + r15;
    float bv = biascat[n0 + cth];
#pragma unroll
    for (int mi = 0; mi < 8; ++mi)
#pragma unroll
      for (int j = 0; j < 4; ++j) {
        int r = m0 + wm * 128 + mi * 16 + ((lane >> 4) << 2) + j;
        outb[((size_t)r << 10) + nbase + cth] = f2bf(acc[mi][ni][j] + bv);
      }
  }
}

// ---------------- V transpose: V (B,S,A) -> Vt (B,A,S) ----------------
__global__ __launch_bounds__(256) void k_transpose(const short* __restrict__ V, short* __restrict__ Vt) {
  int b = blockIdx.z;
  int a0 = blockIdx.x << 6, s0 = blockIdx.y << 6;
  const short* Vb = V + ((size_t)b << 21);
  short* Vtb = Vt + ((size_t)b << 21);
  __shared__ short t[64][65];
  int tx = threadIdx.x & 63, ty = threadIdx.x >> 6;
#pragma unroll
  for (int i = 0; i < 16; ++i)
    t[ty + i * 4][tx] = Vb[((size_t)(s0 + ty + i * 4) << 10) + a0 + tx];
  __syncthreads();
#pragma unroll
  for (int i = 0; i < 16; ++i)
    Vtb[((size_t)(a0 + ty + i * 4) << 11) + s0 + tx] = t[tx][ty + i * 4];
}

// ---------------- QK^T: causal lower-tri 256-tiles, scaled, bf16 scores ----------------
__global__ __launch_bounds__(512, 2) void k_qk(const short* __restrict__ Q, const short* __restrict__ K,
                                               short* __restrict__ Sc) {
  int nt = blockIdx.x, mt = blockIdx.y, b = blockIdx.z;
  if (nt > mt) return;
  __shared__ __align__(16) short lds[65536];
  int tid = threadIdx.x;
  int m0 = mt << 8, n0 = nt << 8;
  const short* Qb = Q + ((size_t)b << 21);
  const short* Kb = K + ((size_t)b << 21);
  f32x4 acc[8][4] = {};
  gemm256_core<1024, 1024>(Qb + (size_t)m0 * 1024, Kb + (size_t)n0 * 1024, 16, lds, acc, tid);
  short* Sb = Sc + ((size_t)b << 22);
  int lane = tid & 63, wid = tid >> 6;
  int wm = wid >> 2, wn = wid & 3;
  int r15 = lane & 15;
#pragma unroll
  for (int mi = 0; mi < 8; ++mi)
#pragma unroll
    for (int ni = 0; ni < 4; ++ni)
#pragma unroll
      for (int j = 0; j < 4; ++j) {
        int r = m0 + wm * 128 + mi * 16 + ((lane >> 4) << 2) + j;
        int c = n0 + wn * 64 + ni * 16 + r15;
        Sb[((size_t)r << 11) + c] = f2bf(acc[mi][ni][j] * 0.03125f);
      }
}

// ---------------- row softmax in-place, causal; zero-fill to 256-tile edge ----------------
__global__ __launch_bounds__(256) void k_softmax(short* __restrict__ Sc) {
  int row = blockIdx.x;
  int b = row >> 11, q = row & 2047;
  short* Pr = Sc + ((size_t)b << 22) + ((size_t)q << 11);
  int T = ((q >> 8) + 1) << 8;          // padded causal length (multiple of 256)
  int tid = threadIdx.x, lane = tid & 63, wid = tid >> 6;
  int k0 = tid << 3;
  float v[8];
  if (k0 < T) {
    short8v raw = *(const short8v*)(Pr + k0);
#pragma unroll
    for (int j = 0; j < 8; ++j) v[j] = (k0 + j <= q) ? bf2f(raw[j]) : -__builtin_inff();
  } else {
#pragma unroll
    for (int j = 0; j < 8; ++j) v[j] = -__builtin_inff();
  }
  float mx = v[0];
#pragma unroll
  for (int j = 1; j < 8; ++j) mx = fmaxf(mx, v[j]);
  for (int off = 1; off < 64; off <<= 1) mx = fmaxf(mx, __shfl_xor(mx, off, 64));
  __shared__ float red[2][4];
  if (lane == 0) red[0][wid] = mx;
  __syncthreads();
  mx = fmaxf(fmaxf(red[0][0], red[0][1]), fmaxf(red[0][2], red[0][3]));
  float e[8], sum = 0.f;
#pragma unroll
  for (int j = 0; j < 8; ++j) {
    e[j] = exp2f((v[j] - mx) * 1.4426950408889634f);
    sum += e[j];
  }
  for (int off = 1; off < 64; off <<= 1) sum += __shfl_xor(sum, off, 64);
  if (lane == 0) red[1][wid] = sum;
  __syncthreads();
  sum = red[1][0] + red[1][1] + red[1][2] + red[1][3];
  float inv = 1.f / sum;
  if (k0 < T) {
    short8v o;
#pragma unroll
    for (int j = 0; j < 8; ++j) o[j] = (k0 + j <= q) ? f2bf(e[j] * inv) : (short)0;
    *(short8v*)(Pr + k0) = o;
  }
}

// ---------------- PV: out (S,B,A) f32 = P (B,S,S) * Vt (B,A,S)^T ----------------
__global__ __launch_bounds__(512, 2) void k_pv(const short* __restrict__ P, const short* __restrict__ Vt,
                                               float* __restrict__ out) {
  int nt = blockIdx.x, mt = blockIdx.y, b = blockIdx.z;
  __shared__ __align__(16) short lds[65536];
  int tid = threadIdx.x;
  int m0 = mt << 8, n0 = nt << 8;
  const short* Pb = P + ((size_t)b << 22);
  const short* Vtb = Vt + ((size_t)b << 21);
  f32x4 acc[8][4] = {};
  gemm256_core<2048, 2048>(Pb + (size_t)m0 * 2048, Vtb + (size_t)n0 * 2048, 4 * (mt + 1), lds, acc, tid);
  int lane = tid & 63, wid = tid >> 6;
  int wm = wid >> 2, wn = wid & 3;
  int r15 = lane & 15;
#pragma unroll
  for (int mi = 0; mi < 8; ++mi)
#pragma unroll
    for (int ni = 0; ni < 4; ++ni)
#pragma unroll
      for (int j = 0; j < 4; ++j) {
        int r = m0 + wm * 128 + mi * 16 + ((lane >> 4) << 2) + j;  // q
        int c = n0 + wn * 64 + ni * 16 + r15;                      // a
        out[((size_t)r << 13) + ((size_t)b << 10) + c] = acc[mi][ni][j];
      }
}

extern "C" void kernel_launch(void* const* d_in, const int* in_sizes, int n_in,
                              void* d_out, int out_size, void* d_ws, size_t ws_size,
                              hipStream_t stream) {
  const float* x  = (const float*)d_in[0];
  const float* Wq = (const float*)d_in[1];
  const float* bq = (const float*)d_in[2];
  const float* Wk = (const float*)d_in[3];
  const float* bk = (const float*)d_in[4];
  const float* Wv = (const float*)d_in[5];
  const float* bv = (const float*)d_in[6];
  float* out = (float*)d_out;
  char* ws = (char*)d_ws;

  short* xb   = (short*)(ws);                    // 33,554,432 B (reused as Vt later)
  short* Wcat = (short*)(ws + 33554432);         //  6,291,456 B
  float* bias = (float*)(ws + 39845888);         //     12,288 B
  short* Q    = (short*)(ws + 39858176);         // 33,554,432 B
  short* K    = (short*)(ws + 73412608);         // 33,554,432 B
  short* V    = (short*)(ws + 106967040);        // 33,554,432 B
  short* Sc   = (short*)(ws + 140521472);        // 67,108,864 B
  short* Vt   = xb;                              // alias: xb dead after k_proj

  k_cast_x<<<16384, 256, 0, stream>>>(x, xb);
  k_cast_w<<<3072, 256, 0, stream>>>(Wq, Wk, Wv, Wcat);
  k_cast_bias<<<12, 256, 0, stream>>>(bq, bk, bv, bias);
  k_proj<<<768, 512, 0, stream>>>(xb, Wcat, bias, Q, K, V);
  k_transpose<<<dim3(16, 32, 8), 256, 0, stream>>>(V, Vt);
  k_qk<<<dim3(8, 8, 8), 512, 0, stream>>>(Q, K, Sc);
  k_softmax<<<16384, 256, 0, stream>>>(Sc);
  k_pv<<<dim3(4, 8, 8), 512, 0, stream>>>(Sc, Vt, out);
}

// Round 3
// 292.716 us; speedup vs baseline: 1.2779x; 1.1302x over previous
//
#include <hip/hip_runtime.h>
#include <hip/hip_bf16.h>
#include <math.h>

typedef short bf16x8 __attribute__((ext_vector_type(8)));
typedef float f32x4 __attribute__((ext_vector_type(4)));
typedef short short4v __attribute__((ext_vector_type(4)));
typedef short short8v __attribute__((ext_vector_type(8)));

__device__ __forceinline__ short f2bf(float f) {
  unsigned u = __builtin_bit_cast(unsigned, f);
  unsigned r = (u + 0x7FFFu + ((u >> 16) & 1u)) >> 16;
  return (short)r;
}
__device__ __forceinline__ float bf2f(short s) {
  unsigned u = ((unsigned)(unsigned short)s) << 16;
  return __builtin_bit_cast(float, u);
}

typedef __attribute__((address_space(1))) const unsigned g_u32;
typedef __attribute__((address_space(3))) unsigned l_u32;
__device__ __forceinline__ void gload_lds16(const short* g, short* l) {
  __builtin_amdgcn_global_load_lds((g_u32*)g, (l_u32*)l, 16, 0, 0);
}

// ---------------- casts ----------------

__global__ __launch_bounds__(256) void k_cast_x(const float* __restrict__ x, short* __restrict__ xb) {
  int tid = blockIdx.x * 256 + threadIdx.x;
  int d4 = tid & 255;
  int sb = tid >> 8;
  int s = sb & 2047;
  int b = sb >> 11;
  float4 v = *((const float4*)(x + (((size_t)s * 8 + b) << 10)) + d4);
  short4v o;
  o.x = f2bf(v.x); o.y = f2bf(v.y); o.z = f2bf(v.z); o.w = f2bf(v.w);
  *((short4v*)(xb + (((size_t)b * 2048 + s) << 10)) + d4) = o;
}

__global__ __launch_bounds__(256) void k_cast_w(const float* __restrict__ Wq, const float* __restrict__ Wk,
                                                const float* __restrict__ Wv, short* __restrict__ Wcat) {
  int tid = blockIdx.x * 256 + threadIdx.x;
  int d4 = tid & 255;
  int n = tid >> 8;
  const float* src = (n < 1024) ? Wq : (n < 2048 ? Wk : Wv);
  int nl = n & 1023;
  float4 v = *((const float4*)(src + ((size_t)nl << 10)) + d4);
  short4v o;
  o.x = f2bf(v.x); o.y = f2bf(v.y); o.z = f2bf(v.z); o.w = f2bf(v.w);
  *((short4v*)(Wcat + ((size_t)n << 10)) + d4) = o;
}

__global__ __launch_bounds__(256) void k_cast_bias(const float* __restrict__ bq, const float* __restrict__ bk,
                                                   const float* __restrict__ bv, float* __restrict__ biascat) {
  int i = blockIdx.x * 256 + threadIdx.x;
  if (i < 3072) biascat[i] = (i < 1024) ? bq[i] : (i < 2048 ? bk[i & 1023] : bv[i & 1023]);
}

// ---------------- 256x256-tile GEMM core, K-split halves + counted vmcnt ----------------
// C[256][256] = A[256, K-contig, LDA] * B^T[256, K-contig, LDB]
// 512 threads = 8 waves (2M x 4N); per-wave 128x64 -> acc[8][4].
// LDS per operand: [2buf][2 K-halves of 32][256 rows][32] bf16 (32768 shorts); A+B = 128 KiB.
// Slot swizzle: slot' = slot ^ ((row>>1)&3) (involution; staged linearly with
// inverse-swizzled global source). 2 words/bank per 16-lane group -> conflict-free.
// Schedule per K-tile t (4 phases):
//  p0: ldA(k0)+ldB(k0,nh0), stage k1(t+1); p1: ldB(k0,nh1), vmcnt(8)
//  p2: ldA(k1)+ldB(k1,nh0), stage k0(t+2); p3: ldB(k1,nh1), vmcnt(8)
// Each half is staged 6 phases before first read; vmcnt(8) drains only the
// oldest half-pair (A+B = 4 loads). Epilogue peels with vmcnt(4)/vmcnt(0).
template <int LDA, int LDB>
__device__ __forceinline__ void gemm256_core(const short* __restrict__ Ag, const short* __restrict__ Bg,
                                             int NT, short* __restrict__ lds, f32x4 (&acc)[8][4], int tid) {
  const int lane = tid & 63;
  const int wid = tid >> 6;
  const int wm = wid >> 2, wn = wid & 3;
  const int r15 = lane & 15;
  const int g = lane >> 4;
  const int co = ((g ^ ((r15 >> 1) & 3)) << 3);   // swizzled element offset within 32-elem row
  short* As = lds;
  short* Bs = lds + 32768;

  auto stage_pair = [&](int bufv, int kkv, int kElem) {
    short* Al = As + (bufv * 2 + kkv) * 8192;
    short* Bl = Bs + (bufv * 2 + kkv) * 8192;
#pragma unroll
    for (int i = 0; i < 2; ++i) {
      int c = i * 512 + tid;
      int r = c >> 2, s = c & 3;
      int gk = kElem + ((s ^ ((r >> 1) & 3)) << 3);
      gload_lds16(Ag + (size_t)r * LDA + gk, Al + c * 8);
    }
#pragma unroll
    for (int i = 0; i < 2; ++i) {
      int c = i * 512 + tid;
      int r = c >> 2, s = c & 3;
      int gk = kElem + ((s ^ ((r >> 1) & 3)) << 3);
      gload_lds16(Bg + (size_t)r * LDB + gk, Bl + c * 8);
    }
  };

  bf16x8 af[8], b0, b1;
  auto lda = [&](int bufv, int kk) {
    const short* Ab = As + ((bufv * 2 + kk) * 256 + wm * 128 + r15) * 32 + co;
#pragma unroll
    for (int mi = 0; mi < 8; ++mi) af[mi] = *(const bf16x8*)(Ab + mi * 512);
  };
  auto ldb = [&](int bufv, int kk, int nh) {
    const short* Bb = Bs + ((bufv * 2 + kk) * 256 + wn * 64 + nh * 32 + r15) * 32 + co;
    b0 = *(const bf16x8*)(Bb);
    b1 = *(const bf16x8*)(Bb + 512);
  };
  auto fire = [&](int nh) {
    __builtin_amdgcn_s_barrier();
    asm volatile("s_waitcnt lgkmcnt(0)" ::: "memory");
    __builtin_amdgcn_sched_barrier(0);
    __builtin_amdgcn_s_setprio(1);
#pragma unroll
    for (int mi = 0; mi < 8; ++mi) {
      acc[mi][nh * 2 + 0] = __builtin_amdgcn_mfma_f32_16x16x32_bf16(af[mi], b0, acc[mi][nh * 2 + 0], 0, 0, 0);
      acc[mi][nh * 2 + 1] = __builtin_amdgcn_mfma_f32_16x16x32_bf16(af[mi], b1, acc[mi][nh * 2 + 1], 0, 0, 0);
    }
    __builtin_amdgcn_s_setprio(0);
  };

  // prologue: k0(0), k1(0), k0(1); drain oldest pair
  stage_pair(0, 0, 0);
  stage_pair(0, 1, 32);
  stage_pair(1, 0, 64);
  asm volatile("s_waitcnt vmcnt(8)" ::: "memory");
  __builtin_amdgcn_s_barrier();

  for (int t = 0; t < NT - 2; ++t) {
    const int buf = t & 1, nbuf = buf ^ 1;
    lda(buf, 0); ldb(buf, 0, 0); stage_pair(nbuf, 1, ((t + 1) << 6) + 32);
    fire(0);
    __builtin_amdgcn_s_barrier();
    ldb(buf, 0, 1);
    fire(1);
    asm volatile("s_waitcnt vmcnt(8)" ::: "memory");
    __builtin_amdgcn_s_barrier();
    lda(buf, 1); ldb(buf, 1, 0); stage_pair(buf, 0, (t + 2) << 6);
    fire(0);
    __builtin_amdgcn_s_barrier();
    ldb(buf, 1, 1);
    fire(1);
    asm volatile("s_waitcnt vmcnt(8)" ::: "memory");
    __builtin_amdgcn_s_barrier();
  }
  {  // t = NT-2: no k0(t+2) stage; final-tile k0 guarded by vmcnt(4)
    const int t = NT - 2, buf = t & 1, nbuf = buf ^ 1;
    lda(buf, 0); ldb(buf, 0, 0); stage_pair(nbuf, 1, ((t + 1) << 6) + 32);
    fire(0);
    __builtin_amdgcn_s_barrier();
    ldb(buf, 0, 1);
    fire(1);
    asm volatile("s_waitcnt vmcnt(8)" ::: "memory");
    __builtin_amdgcn_s_barrier();
    lda(buf, 1); ldb(buf, 1, 0);
    fire(0);
    __builtin_amdgcn_s_barrier();
    ldb(buf, 1, 1);
    fire(1);
    asm volatile("s_waitcnt vmcnt(4)" ::: "memory");
    __builtin_amdgcn_s_barrier();
  }
  {  // t = NT-1: no stages; k1 guarded by vmcnt(0)
    const int buf = (NT - 1) & 1;
    lda(buf, 0); ldb(buf, 0, 0);
    fire(0);
    __builtin_amdgcn_s_barrier();
    ldb(buf, 0, 1);
    fire(1);
    asm volatile("s_waitcnt vmcnt(0)" ::: "memory");
    __builtin_amdgcn_s_barrier();
    lda(buf, 1); ldb(buf, 1, 0);
    fire(0);
    __builtin_amdgcn_s_barrier();
    ldb(buf, 1, 1);
    fire(1);
    __builtin_amdgcn_s_barrier();
  }
}

// ---------------- QKV projection: (16384,3072) = Xb (16384,1024) * Wcat^T + bias ----------------
// Q, K stored (B,S,A) bf16; V stored TRANSPOSED as Vt (B,A,S) bf16 (kills the transpose kernel).
__global__ __launch_bounds__(512, 1) void k_proj(const short* __restrict__ Xb, const short* __restrict__ Wc,
                                                 const float* __restrict__ biascat,
                                                 short* __restrict__ Q, short* __restrict__ K, short* __restrict__ Vt) {
  __shared__ __align__(16) short lds[65536];
  int tid = threadIdx.x;
  int wg = blockIdx.x;                       // 768 blocks
  int swz = (wg & 7) * 96 + (wg >> 3);       // XCD swizzle (768 % 8 == 0, bijective)
  int mt = swz / 12, nt = swz % 12;
  int m0 = mt << 8, n0 = nt << 8;
  f32x4 acc[8][4] = {};
  gemm256_core<1024, 1024>(Xb + (size_t)m0 * 1024, Wc + (size_t)n0 * 1024, 16, lds, acc, tid);
  int lane = tid & 63, wid = tid >> 6;
  int wm = wid >> 2, wn = wid & 3;
  int r15 = lane & 15;
  int which = n0 >> 10;
  int nbase = n0 & 1023;
  if (which == 2) {
    // write V transposed: Vt[b][a][s], 4 consecutive s per lane -> 8B stores
#pragma unroll
    for (int ni = 0; ni < 4; ++ni) {
      int cth = wn * 64 + ni * 16 + r15;
      int a = nbase + cth;
      float bv = biascat[n0 + cth];
#pragma unroll
      for (int mi = 0; mi < 8; ++mi) {
        int r = m0 + wm * 128 + mi * 16 + ((lane >> 4) << 2);
        int b = r >> 11, s = r & 2047;
        short4v o;
#pragma unroll
        for (int j = 0; j < 4; ++j) o[j] = f2bf(acc[mi][ni][j] + bv);
        *(short4v*)(Vt + ((size_t)b << 21) + ((size_t)a << 11) + s) = o;
      }
    }
  } else {
    short* outb = (which == 0) ? Q : K;
#pragma unroll
    for (int ni = 0; ni < 4; ++ni) {
      int cth = wn * 64 + ni * 16 + r15;
      float bv = biascat[n0 + cth];
#pragma unroll
      for (int mi = 0; mi < 8; ++mi)
#pragma unroll
        for (int j = 0; j < 4; ++j) {
          int r = m0 + wm * 128 + mi * 16 + ((lane >> 4) << 2) + j;
          outb[((size_t)r << 10) + nbase + cth] = f2bf(acc[mi][ni][j] + bv);
        }
    }
  }
}

// ---------------- QK^T: causal lower-tri 256-tiles, scaled, bf16 scores ----------------
__global__ __launch_bounds__(512, 1) void k_qk(const short* __restrict__ Q, const short* __restrict__ K,
                                               short* __restrict__ Sc) {
  int nt = blockIdx.x, mt = blockIdx.y, b = blockIdx.z;
  if (nt > mt) return;
  __shared__ __align__(16) short lds[65536];
  int tid = threadIdx.x;
  int m0 = mt << 8, n0 = nt << 8;
  const short* Qb = Q + ((size_t)b << 21);
  const short* Kb = K + ((size_t)b << 21);
  f32x4 acc[8][4] = {};
  gemm256_core<1024, 1024>(Qb + (size_t)m0 * 1024, Kb + (size_t)n0 * 1024, 16, lds, acc, tid);
  short* Sb = Sc + ((size_t)b << 22);
  int lane = tid & 63, wid = tid >> 6;
  int wm = wid >> 2, wn = wid & 3;
  int r15 = lane & 15;
#pragma unroll
  for (int mi = 0; mi < 8; ++mi)
#pragma unroll
    for (int ni = 0; ni < 4; ++ni)
#pragma unroll
      for (int j = 0; j < 4; ++j) {
        int r = m0 + wm * 128 + mi * 16 + ((lane >> 4) << 2) + j;
        int c = n0 + wn * 64 + ni * 16 + r15;
        Sb[((size_t)r << 11) + c] = f2bf(acc[mi][ni][j] * 0.03125f);
      }
}

// ---------------- row softmax in-place, causal; zero-fill to 256-tile edge ----------------
__global__ __launch_bounds__(256) void k_softmax(short* __restrict__ Sc) {
  int row = blockIdx.x;
  int b = row >> 11, q = row & 2047;
  short* Pr = Sc + ((size_t)b << 22) + ((size_t)q << 11);
  int T = ((q >> 8) + 1) << 8;          // padded causal length (multiple of 256)
  int tid = threadIdx.x, lane = tid & 63, wid = tid >> 6;
  int k0 = tid << 3;
  float v[8];
  if (k0 < T) {
    short8v raw = *(const short8v*)(Pr + k0);
#pragma unroll
    for (int j = 0; j < 8; ++j) v[j] = (k0 + j <= q) ? bf2f(raw[j]) : -__builtin_inff();
  } else {
#pragma unroll
    for (int j = 0; j < 8; ++j) v[j] = -__builtin_inff();
  }
  float mx = v[0];
#pragma unroll
  for (int j = 1; j < 8; ++j) mx = fmaxf(mx, v[j]);
  for (int off = 1; off < 64; off <<= 1) mx = fmaxf(mx, __shfl_xor(mx, off, 64));
  __shared__ float red[2][4];
  if (lane == 0) red[0][wid] = mx;
  __syncthreads();
  mx = fmaxf(fmaxf(red[0][0], red[0][1]), fmaxf(red[0][2], red[0][3]));
  float e[8], sum = 0.f;
#pragma unroll
  for (int j = 0; j < 8; ++j) {
    e[j] = exp2f((v[j] - mx) * 1.4426950408889634f);
    sum += e[j];
  }
  for (int off = 1; off < 64; off <<= 1) sum += __shfl_xor(sum, off, 64);
  if (lane == 0) red[1][wid] = sum;
  __syncthreads();
  sum = red[1][0] + red[1][1] + red[1][2] + red[1][3];
  float inv = 1.f / sum;
  if (k0 < T) {
    short8v o;
#pragma unroll
    for (int j = 0; j < 8; ++j) o[j] = (k0 + j <= q) ? f2bf(e[j] * inv) : (short)0;
    *(short8v*)(Pr + k0) = o;
  }
}

// ---------------- PV: out (S,B,A) f32 = P (B,S,S) * Vt (B,A,S)^T ----------------
__global__ __launch_bounds__(512, 1) void k_pv(const short* __restrict__ P, const short* __restrict__ Vt,
                                               float* __restrict__ out) {
  int nt = blockIdx.x, mt = blockIdx.y, b = blockIdx.z;
  __shared__ __align__(16) short lds[65536];
  int tid = threadIdx.x;
  int m0 = mt << 8, n0 = nt << 8;
  const short* Pb = P + ((size_t)b << 22);
  const short* Vtb = Vt + ((size_t)b << 21);
  f32x4 acc[8][4] = {};
  gemm256_core<2048, 2048>(Pb + (size_t)m0 * 2048, Vtb + (size_t)n0 * 2048, 4 * (mt + 1), lds, acc, tid);
  int lane = tid & 63, wid = tid >> 6;
  int wm = wid >> 2, wn = wid & 3;
  int r15 = lane & 15;
#pragma unroll
  for (int mi = 0; mi < 8; ++mi)
#pragma unroll
    for (int ni = 0; ni < 4; ++ni)
#pragma unroll
      for (int j = 0; j < 4; ++j) {
        int r = m0 + wm * 128 + mi * 16 + ((lane >> 4) << 2) + j;  // q
        int c = n0 + wn * 64 + ni * 16 + r15;                      // a
        out[((size_t)r << 13) + ((size_t)b << 10) + c] = acc[mi][ni][j];
      }
}

extern "C" void kernel_launch(void* const* d_in, const int* in_sizes, int n_in,
                              void* d_out, int out_size, void* d_ws, size_t ws_size,
                              hipStream_t stream) {
  const float* x  = (const float*)d_in[0];
  const float* Wq = (const float*)d_in[1];
  const float* bq = (const float*)d_in[2];
  const float* Wk = (const float*)d_in[3];
  const float* bk = (const float*)d_in[4];
  const float* Wv = (const float*)d_in[5];
  const float* bv = (const float*)d_in[6];
  float* out = (float*)d_out;
  char* ws = (char*)d_ws;

  short* xb   = (short*)(ws);                    // 33,554,432 B
  short* Wcat = (short*)(ws + 33554432);         //  6,291,456 B
  float* bias = (float*)(ws + 39845888);         //     12,288 B
  short* Q    = (short*)(ws + 39858176);         // 33,554,432 B
  short* K    = (short*)(ws + 73412608);         // 33,554,432 B
  short* Vt   = (short*)(ws + 106967040);        // 33,554,432 B (written transposed by k_proj)
  short* Sc   = (short*)(ws + 140521472);        // 67,108,864 B

  k_cast_x<<<16384, 256, 0, stream>>>(x, xb);
  k_cast_w<<<3072, 256, 0, stream>>>(Wq, Wk, Wv, Wcat);
  k_cast_bias<<<12, 256, 0, stream>>>(bq, bk, bv, bias);
  k_proj<<<768, 512, 0, stream>>>(xb, Wcat, bias, Q, K, Vt);
  k_qk<<<dim3(8, 8, 8), 512, 0, stream>>>(Q, K, Sc);
  k_softmax<<<16384, 256, 0, stream>>>(Sc);
  k_pv<<<dim3(4, 8, 8), 512, 0, stream>>>(Sc, Vt, out);
}